// Round 6
// baseline (935.504 us; speedup 1.0000x reference)
//
#include <hip/hip_runtime.h>
#include <hip/hip_bf16.h>

typedef __hip_bfloat16 bf16;
typedef __attribute__((ext_vector_type(4))) float f32x4;
typedef __attribute__((ext_vector_type(8))) short short8;

#define T_ 8
#define N_ 1152
#define C_ 768
#define H_ 12
#define DH_ 64
#define MLP_ 3072
#define LRU_ 768
#define NIMG_ 1024
#define M_ (T_*N_)       // 9216 tokens

__device__ __forceinline__ float b2f(bf16 v){ return __bfloat162float(v); }
__device__ __forceinline__ bf16  f2b(float f){ return __float2bfloat16(f); }
// fast tanh-gelu: tanh(u) = 1 - 2/(e^{2u}+1) via v_exp_f32; saturates correctly at +/-inf
__device__ __forceinline__ float gelu_tanh(float x){
  float x3 = x*x*x;
  float z = 1.5957691216057308f*(x + 0.044715f*x3);   // 2*0.7978845608028654
  float e = __expf(z);
  float t = 1.f - 2.f/(e + 1.f);
  return 0.5f*x*(1.f + t);
}
__device__ __forceinline__ void gll16(const void* g, void* l) {
  __builtin_amdgcn_global_load_lds((const __attribute__((address_space(1))) void*)g,
                                   (__attribute__((address_space(3))) void*)l, 16, 0, 0);
}
__device__ __forceinline__ f32x4 mfma16(short8 a, short8 b, f32x4 c) {
  return __builtin_amdgcn_mfma_f32_16x16x32_bf16(a, b, c, 0, 0, 0);
}

// ---------------- transpose-convert: W[K][N] fp32 -> Wt[(n*rs+ro)][K] bf16 ----------------
__global__ __launch_bounds__(256)
void convertT(const float* __restrict__ W, bf16* __restrict__ Wt, int Kd, int Nd,
              int rs, int ro) {
  __shared__ float tile[64][65];
  int k0 = blockIdx.y * 64, n0 = blockIdx.x * 64;
  int tid = threadIdx.x;
  int c = tid & 63, rr = tid >> 6;
  #pragma unroll
  for (int i = 0; i < 16; i++) {
    int r = rr * 16 + i;
    tile[r][c] = W[(size_t)(k0 + r) * Nd + n0 + c];
  }
  __syncthreads();
  #pragma unroll
  for (int i = 0; i < 16; i++) {
    int n = rr * 16 + i;
    Wt[(size_t)((n0 + n) * rs + ro) * Kd + k0 + c] = f2b(tile[c][n]);
  }
}

// ---------------- gates weight interleave: GW[h][2e+s][d] bf16, GB[h][2e+s] ----------------
__global__ __launch_bounds__(256)
void convert_gw(const float* __restrict__ igw, const float* __restrict__ agw,
                const float* __restrict__ igb, const float* __restrict__ agb,
                bf16* __restrict__ GW, float* __restrict__ GB) {
  int h = blockIdx.x;
  for (int idx = threadIdx.x; idx < 128 * 64; idx += 256) {
    int rowc = idx >> 6;          // 2e+s
    int d    = idx & 63;
    int e    = rowc >> 1;
    const float* W = (rowc & 1) ? agw : igw;
    GW[((size_t)h * 128 + rowc) * 64 + d] = f2b(W[((size_t)h * 64 + d) * 64 + e]);
  }
  if (threadIdx.x < 128) {
    int rowc = threadIdx.x;
    GB[h * 128 + rowc] = ((rowc & 1) ? agb : igb)[h * 64 + (rowc >> 1)];
  }
}

// ---------------- MFMA GEMM: A[M,K] bf16 x Wt[N,K] bf16 -> out[M,N] ----------------
// K is compile-time: static k-loop (2x unrolled, static LDS buffer indices) kills the
// VALU address/select overhead (R5: VALUBusy 47% was the co-bottleneck).
// EPI: 0 = bf16 out (+bias, opt gelu); 1 = fp32 out = v+bias+bias2[o] (resid; may equal out);
//      2 = bf16 out scattered to V-transposed layout [t,h][d][n];
//      3 = interleaved gated-FFW: out[row][col>>1] = gelu(even+b0)*(odd+b1), bf16, width Nd/2
//      4 = split-bias merged pair: col<Nd/2 uses bias[], else bias2[]; gelu on first half iff ACT
template<int EPI, int ACT, int K>
__global__ __launch_bounds__(256)
void mgemm(const bf16* __restrict__ A, const bf16* __restrict__ Wt,
           const float* __restrict__ bias, const float* __restrict__ bias2,
           void* __restrict__ outp, int Nd) {
  __shared__ bf16 As[2][128][32];
  __shared__ bf16 Bs[2][128][32];
  constexpr int NT = K >> 5;       // 24 or 96 (always even)
  int tid = threadIdx.x;
  int wave = tid >> 6, lane = tid & 63;
  int wm = wave >> 1, wn = wave & 1;
  int ln15 = lane & 15, quad = lane >> 4;
  int row0 = blockIdx.y * 128, col0 = blockIdx.x * 128;
  const bf16* ag = A  + (size_t)(row0 + wave*32 + (lane>>2)) * K + (lane&3)*8;
  const bf16* bg = Wt + (size_t)(col0 + wave*32 + (lane>>2)) * K + (lane&3)*8;
  f32x4 zero = {0.f, 0.f, 0.f, 0.f};
  f32x4 acc[4][4];
  #pragma unroll
  for (int i = 0; i < 4; i++)
    #pragma unroll
    for (int j = 0; j < 4; j++) acc[i][j] = zero;

  auto stage = [&](int kt, int buf) {
    int kk = kt << 5;
    gll16(ag + kk,          &As[buf][wave*32][0]);
    gll16(ag + 16*K + kk,   &As[buf][wave*32 + 16][0]);
    gll16(bg + kk,          &Bs[buf][wave*32][0]);
    gll16(bg + 16*K + kk,   &Bs[buf][wave*32 + 16][0]);
  };
  auto compute = [&](int buf) {
    short8 af[4], bf_[4];
    #pragma unroll
    for (int i = 0; i < 4; i++)
      af[i] = *(const short8*)&As[buf][wm*64 + i*16 + ln15][quad*8];
    #pragma unroll
    for (int i = 0; i < 4; i++)
      bf_[i] = *(const short8*)&Bs[buf][wn*64 + i*16 + ln15][quad*8];
    #pragma unroll
    for (int i = 0; i < 4; i++)
      #pragma unroll
      for (int j = 0; j < 4; j++)
        acc[i][j] = mfma16(af[i], bf_[j], acc[i][j]);
  };

  stage(0, 0);
  __syncthreads();
  for (int t = 0; t < NT; t += 2) {
    stage(t + 1, 1);                 // t+1 <= NT-1 always
    compute(0);
    __syncthreads();
    if (t + 2 < NT) stage(t + 2, 0);
    compute(1);
    __syncthreads();
  }

  #pragma unroll
  for (int i = 0; i < 4; i++) {
    #pragma unroll
    for (int j = 0; j < 4; j++) {
      int col = col0 + wn*64 + j*16 + ln15;
      float bv;
      if (EPI == 3)      bv = bias[(col & 1) * (Nd >> 1) + (col >> 1)];
      else if (EPI == 4) bv = (col < (Nd >> 1)) ? bias[col] : bias2[col - (Nd >> 1)];
      else               bv = bias[col];
      #pragma unroll
      for (int r = 0; r < 4; r++) {
        int row = row0 + wm*64 + i*16 + quad*4 + r;
        float v = acc[i][j][r] + bv;
        if (EPI == 3) {
          float pv = __shfl_xor(v, 1, 64);
          if ((lane & 1) == 0)
            ((bf16*)outp)[(size_t)row * (Nd >> 1) + (col >> 1)] = f2b(gelu_tanh(v) * pv);
        } else if (EPI == 4) {
          if (ACT && col < (Nd >> 1)) v = gelu_tanh(v);
          ((bf16*)outp)[(size_t)row * Nd + col] = f2b(v);
        } else {
          if (ACT) v = gelu_tanh(v);
          if (EPI == 0) {
            ((bf16*)outp)[(size_t)row * Nd + col] = f2b(v);
          } else if (EPI == 1) {
            size_t o = (size_t)row * Nd + col;
            ((float*)outp)[o] = v + bias2[o];
          } else if (EPI == 2) {
            int tt = row / N_; int nn = row - tt * N_;
            ((bf16*)outp)[(((size_t)tt * H_ + (col >> 6)) * 64 + (col & 63)) * N_ + nn] = f2b(v);
          }
        }
      }
    }
  }
}

// ---------------- norm: one wave per token; fp32 in, bf16 out ----------------
template<int LN>
__global__ __launch_bounds__(256)
void norm_kernel(const float* __restrict__ inp, const float* __restrict__ s,
                 const float* __restrict__ b, bf16* __restrict__ out) {
  int wid  = threadIdx.x >> 6;
  int lane = threadIdx.x & 63;
  int tok  = blockIdx.x * 4 + wid;
  float v[12];
  float sum = 0.f, sq = 0.f;
  #pragma unroll
  for (int i = 0; i < 12; i++) {
    int c = lane + i * 64;
    float x = inp[(size_t)tok*C_ + c];
    v[i] = x; sum += x; sq += x * x;
  }
  #pragma unroll
  for (int o = 32; o > 0; o >>= 1) {
    sum += __shfl_xor(sum, o, 64);
    sq  += __shfl_xor(sq, o, 64);
  }
  float scale, mean = 0.f;
  if (LN) {
    mean = sum * (1.f / C_);
    float var = sq * (1.f / C_) - mean * mean;
    scale = rsqrtf(var + 1e-6f);
  } else {
    scale = rsqrtf(sq * (1.f / C_) + 1e-6f);
  }
  #pragma unroll
  for (int i = 0; i < 12; i++) {
    int c = lane + i * 64;
    float sc = s[c];
    float r;
    if (LN) r = (v[i] - mean) * scale * sc + b[c];
    else    r = v[i] * scale * (1.f + sc);
    out[(size_t)tok*C_ + c] = f2b(r);
  }
}

// ---------------- causal depthwise temporal conv (width 4); u at [tok]*us + uo ----------------
__global__ __launch_bounds__(256)
void conv_kernel(const bf16* __restrict__ u0, const float* __restrict__ cw,
                 const float* __restrict__ cb, bf16* __restrict__ uc, int us, int uo) {
  int idx = blockIdx.x * 256 + threadIdx.x;
  int ch  = idx % LRU_;
  int tok = idx / LRU_;
  int n = tok % N_;
  int t = tok / N_;
  float acc = cb[ch];
  #pragma unroll
  for (int i = 0; i < 4; i++) {
    int tt = t - 3 + i;
    if (tt >= 0)
      acc += cw[i*LRU_ + ch] * b2f(u0[(size_t)(tt*N_ + n)*us + uo + ch]);
  }
  uc[idx] = f2b(acc);
}

// ---------------- RG-LRU gates via MFMA (block-diagonal GEMM, interleaved ig/ag) ----------------
__global__ __launch_bounds__(256)
void gates_mfma(const bf16* __restrict__ uc, const bf16* __restrict__ GW,
                const float* __restrict__ GB, const float* __restrict__ ap,
                bf16* __restrict__ a_out, bf16* __restrict__ nx_out) {
  __shared__ bf16 As[128][64];   // u[row0+.., h*64 + d]  -> later: nx results
  __shared__ bf16 Bs[128][64];   // GW[h][2e+s][d]        -> later: a results
  int tid = threadIdx.x;
  int wave = tid >> 6, lane = tid & 63;
  int wm = wave >> 1, wn = wave & 1;
  int ln15 = lane & 15, quad = lane >> 4;
  int row0 = blockIdx.x * 128;
  int h = blockIdx.y;
  #pragma unroll
  for (int i = 0; i < 4; i++) {
    int chunk = wave * 4 + i;
    gll16(uc + (size_t)(row0 + chunk*8 + (lane>>3)) * LRU_ + h*DH_ + (lane&7)*8,
          &As[chunk*8][0]);
    gll16(GW + (size_t)h*128*64 + chunk*512 + lane*8, &Bs[chunk*8][0]);
  }
  __syncthreads();
  f32x4 zero = {0.f, 0.f, 0.f, 0.f};
  f32x4 acc[4][4];
  #pragma unroll
  for (int i = 0; i < 4; i++)
    #pragma unroll
    for (int j = 0; j < 4; j++) acc[i][j] = zero;
  short8 af0[4], af1[4], bf0[4], bf1[4];
  #pragma unroll
  for (int i = 0; i < 4; i++) {
    af0[i] = *(const short8*)&As[wm*64 + i*16 + ln15][quad*8];
    af1[i] = *(const short8*)&As[wm*64 + i*16 + ln15][32 + quad*8];
    bf0[i] = *(const short8*)&Bs[wn*64 + i*16 + ln15][quad*8];
    bf1[i] = *(const short8*)&Bs[wn*64 + i*16 + ln15][32 + quad*8];
  }
  #pragma unroll
  for (int i = 0; i < 4; i++)
    #pragma unroll
    for (int j = 0; j < 4; j++) {
      acc[i][j] = mfma16(af0[i], bf0[j], acc[i][j]);
      acc[i][j] = mfma16(af1[i], bf1[j], acc[i][j]);
    }
  __syncthreads();   // all waves done reading As/Bs fragments before overwrite

  int t_is0 = (row0 < N_);   // 128 | N_, so tiles never cross a t boundary
  int odd = lane & 1;
  float bvj[4], spj[4];
  #pragma unroll
  for (int j = 0; j < 4; j++) {
    int col = wn*64 + j*16 + ln15;
    bvj[j] = GB[h*128 + col];
    int e = col >> 1;
    float apv = ap[h*DH_ + e];
    spj[j] = (apv > 20.f) ? apv : log1pf(__expf(apv));
  }
  #pragma unroll
  for (int i = 0; i < 4; i++) {
    #pragma unroll
    for (int j = 0; j < 4; j++) {
      int col = wn*64 + j*16 + ln15;            // 2e+s; parity == lane parity
      int e = col >> 1;
      #pragma unroll
      for (int r = 0; r < 4; r++) {
        int lr = wm*64 + i*16 + quad*4 + r;     // local row
        float v = acc[i][j][r] + bvj[j];
        float g = 1.f / (1.f + __expf(-v));     // even: gx, odd: ga
        float mult = 1.f;
        if (odd) {
          float log_a = -8.f * g * spj[j];
          float a = __expf(log_a);
          mult = sqrtf(fmaxf(1.f - a*a, 0.f));  // exp(2*log_a) == a*a
          if (t_is0) { a = 0.f; mult = 1.f; }
          Bs[lr][e] = f2b(a);
        }
        float mp = __shfl_xor(mult, 1, 64);     // odd's mult -> even lane
        if (!odd) {
          float uv = b2f(As[lr][e]);            // u value lives in the A tile
          As[lr][e] = f2b(uv * g * mp);
        }
      }
    }
  }
  __syncthreads();
  // coalesced stores: 8 lanes x 16B = one full 128B row per 8 lanes
  int rr = tid >> 3, cc = (tid & 7) * 8;
  #pragma unroll
  for (int it = 0; it < 4; it++) {
    int row = it * 32 + rr;
    size_t o = (size_t)(row0 + row) * LRU_ + h*DH_ + cc;
    *(short8*)(nx_out + o) = *(const short8*)&As[row][cc];
    *(short8*)(a_out  + o) = *(const short8*)&Bs[row][cc];
  }
}

// ---------------- RG-LRU scan over t=8, fused h*y; y at [tok]*ys ----------------
__global__ __launch_bounds__(256)
void scan_kernel(const bf16* __restrict__ a, const bf16* __restrict__ nx,
                 const bf16* __restrict__ y, bf16* __restrict__ hy, int ys) {
  int idx = blockIdx.x * 256 + threadIdx.x;
  int n  = idx / LRU_;
  int ch = idx % LRU_;
  float h = 0.f;
  #pragma unroll
  for (int t = 0; t < T_; t++) {
    size_t p = (size_t)(t*N_ + n) * LRU_ + ch;
    h = b2f(a[p]) * h + b2f(nx[p]);
    hy[p] = f2b(h * b2f(y[(size_t)(t*N_ + n) * ys + ch]));
  }
}

// ---------------- flash attention (MFMA), mask_image2image ----------------
// QK packed [tok][1536]: q at +0, k at +768 (both offset h*64). Vt: [t*H+h][64 d][1152 n].
__global__ __launch_bounds__(256)
void fattn(const bf16* __restrict__ QK, const bf16* __restrict__ Vt,
           bf16* __restrict__ O) {
  __shared__ bf16 Ks[128][64];      // [key][d]
  __shared__ bf16 VTs[64][128];     // [d][key]
  __shared__ bf16 Ps[4][16][128];   // per-wave P
  int qb = blockIdx.x, th = blockIdx.y;
  int h = th % H_, t = th / H_;
  int wave = threadIdx.x >> 6, lane = threadIdx.x & 63;
  int ln15 = lane & 15, quad = lane >> 4;
  int q0, kv0, nch;
  if (qb < 16) { q0 = qb * 64;            kv0 = NIMG_; nch = 1; }
  else         { q0 = NIMG_ + (qb-16)*64; kv0 = 0;     nch = 9; }
  int qw = q0 + wave * 16;
  const bf16* qp = QK + (size_t)(t*N_ + qw + ln15) * 1536 + h*DH_ + quad*8;
  short8 aq0 = *(const short8*)qp;
  short8 aq1 = *(const short8*)(qp + 32);
  f32x4 zero = {0.f, 0.f, 0.f, 0.f};
  f32x4 oacc[4];
  #pragma unroll
  for (int d = 0; d < 4; d++) oacc[d] = zero;
  float mi[4], li[4];
  #pragma unroll
  for (int r = 0; r < 4; r++) { mi[r] = -1e30f; li[r] = 0.f; }

  for (int ch = 0; ch < nch; ch++) {
    int kb = t*N_ + kv0 + ch*128;
    #pragma unroll
    for (int i = 0; i < 4; i++) {
      int r = wave*32 + i*8;
      gll16(QK + (size_t)(kb + r + (lane>>3))*1536 + 768 + h*DH_ + (lane&7)*8, &Ks[r][0]);
    }
    #pragma unroll
    for (int i = 0; i < 4; i++) {
      int d = wave*16 + i*4;
      gll16(Vt + ((size_t)(t*H_ + h)*64 + d + (lane>>4))*N_ + kv0 + ch*128 + ln15*8,
            &VTs[d][0]);
    }
    __syncthreads();
    // S = Q K^T * 0.125
    f32x4 s[8];
    #pragma unroll
    for (int nt = 0; nt < 8; nt++) {
      short8 b0 = *(const short8*)&Ks[nt*16 + ln15][quad*8];
      short8 b1 = *(const short8*)&Ks[nt*16 + ln15][32 + quad*8];
      f32x4 c_ = zero;
      c_ = mfma16(aq0, b0, c_);
      c_ = mfma16(aq1, b1, c_);
      #pragma unroll
      for (int r = 0; r < 4; r++) s[nt][r] = c_[r] * 0.125f;
    }
    // online softmax
    float alpha[4], lsum[4];
    #pragma unroll
    for (int r = 0; r < 4; r++) {
      float m_ = s[0][r];
      #pragma unroll
      for (int nt = 1; nt < 8; nt++) m_ = fmaxf(m_, s[nt][r]);
      #pragma unroll
      for (int o = 1; o < 16; o <<= 1) m_ = fmaxf(m_, __shfl_xor(m_, o, 64));
      float mnew = fmaxf(mi[r], m_);
      alpha[r] = __expf(mi[r] - mnew);
      mi[r] = mnew;
      lsum[r] = 0.f;
    }
    #pragma unroll
    for (int nt = 0; nt < 8; nt++)
      #pragma unroll
      for (int r = 0; r < 4; r++) {
        float p = __expf(s[nt][r] - mi[r]);
        s[nt][r] = p; lsum[r] += p;
      }
    #pragma unroll
    for (int r = 0; r < 4; r++) {
      float l_ = lsum[r];
      #pragma unroll
      for (int o = 1; o < 16; o <<= 1) l_ += __shfl_xor(l_, o, 64);
      li[r] = li[r] * alpha[r] + l_;
    }
    // P -> LDS (C-layout -> A-layout round trip)
    #pragma unroll
    for (int nt = 0; nt < 8; nt++)
      #pragma unroll
      for (int r = 0; r < 4; r++)
        Ps[wave][quad*4 + r][nt*16 + ln15] = f2b(s[nt][r]);
    #pragma unroll
    for (int d = 0; d < 4; d++)
      #pragma unroll
      for (int r = 0; r < 4; r++) oacc[d][r] *= alpha[r];
    // O += P V
    #pragma unroll
    for (int ks = 0; ks < 4; ks++) {
      short8 pa = *(const short8*)&Ps[wave][ln15][ks*32 + quad*8];
      #pragma unroll
      for (int dt = 0; dt < 4; dt++) {
        short8 vb = *(const short8*)&VTs[dt*16 + ln15][ks*32 + quad*8];
        oacc[dt] = mfma16(pa, vb, oacc[dt]);
      }
    }
    __syncthreads();
  }
  #pragma unroll
  for (int dt = 0; dt < 4; dt++)
    #pragma unroll
    for (int r = 0; r < 4; r++)
      O[(size_t)(t*N_ + qw + quad*4 + r)*C_ + h*DH_ + dt*16 + ln15]
        = f2b(oacc[dt][r] / li[r]);
}

extern "C" void kernel_launch(void* const* d_in, const int* in_sizes, int n_in,
                              void* d_out, int out_size, void* d_ws, size_t ws_size,
                              hipStream_t stream) {
  (void)in_sizes; (void)n_in; (void)out_size; (void)ws_size;
  const float* x        = (const float*)d_in[0];
  const float* tpre     = (const float*)d_in[1];
  const float* w_y      = (const float*)d_in[2];
  const float* b_y      = (const float*)d_in[3];
  const float* w_x      = (const float*)d_in[4];
  const float* b_x      = (const float*)d_in[5];
  const float* conv_w   = (const float*)d_in[6];
  const float* conv_b   = (const float*)d_in[7];
  const float* a_param  = (const float*)d_in[8];
  const float* ig_w     = (const float*)d_in[9];
  const float* ig_b     = (const float*)d_in[10];
  const float* ag_w     = (const float*)d_in[11];
  const float* ag_b     = (const float*)d_in[12];
  const float* w_out    = (const float*)d_in[13];
  const float* b_out    = (const float*)d_in[14];
  const float* cpre     = (const float*)d_in[15];
  const float* ffw_up_w = (const float*)d_in[16];
  const float* ffw_up_b = (const float*)d_in[17];
  const float* ffw_dn_w = (const float*)d_in[18];
  const float* ffw_dn_b = (const float*)d_in[19];
  const float* ln1_s    = (const float*)d_in[20];
  const float* ln1_b    = (const float*)d_in[21];
  const float* wq       = (const float*)d_in[22];
  const float* bq       = (const float*)d_in[23];
  const float* wk       = (const float*)d_in[24];
  const float* bk       = (const float*)d_in[25];
  const float* wv       = (const float*)d_in[26];
  const float* bv       = (const float*)d_in[27];
  const float* wo       = (const float*)d_in[28];
  const float* bo       = (const float*)d_in[29];
  const float* ln2_s    = (const float*)d_in[30];
  const float* ln2_b    = (const float*)d_in[31];
  const float* mlp_w1   = (const float*)d_in[32];
  const float* mlp_b1   = (const float*)d_in[33];
  const float* mlp_w2   = (const float*)d_in[34];
  const float* mlp_b2   = (const float*)d_in[35];

  const size_t MC = (size_t)M_ * C_;
  const size_t W68 = (size_t)C_ * C_;          // 589824 (768x768)
  const size_t WUP = (size_t)C_ * MLP_;        // 2.36M
  // ws layout: B0,B1,B2,BV bf16 M*C; F0,F1 fp32 M*C (F0:F1 = 4*MC bf16-equivalent)
  bf16* B0 = (bf16*)d_ws;
  bf16* B1 = B0 + MC;
  bf16* B2 = B1 + MC;
  bf16* BV = B2 + MC;
  float* F0 = (float*)(BV + MC);
  float* F1 = F0 + MC;
  bf16* F0b = (bf16*)F0;        // 56.6 MB scratch region
  bf16* B0b = (bf16*)B0;        // bf16 view of B0:B1 (28.3 MB)
  float* xsF = (float*)B0;      // fp32 view of B0:B1 (M x C fp32 = 28.3 MB)
  float* outF = (float*)d_out;  // resid / xs2 / final out (fp32 M x C)
  // gates weights live at F1 (yu occupies F0b[0,2MC) = bytes [0,4MC) -> ends exactly at F1)
  bf16*  GW = (bf16*)F1;                        // [H][128][64] bf16 = 2.36 MB
  float* GB = (float*)(GW + (size_t)H_*128*64); // [H][128] fp32

  dim3 blk(256);
  dim3 gN768(C_/128, M_/128);          // (6, 72)
  dim3 g1536(1536/128, M_/128);        // (12, 72)
  dim3 cv768(12, 12);                  // convertT 768x768
  dim3 cvUp(48, 12);                   // 768x3072
  dim3 cvDn(12, 48);                   // 3072x768

  // ================= temporal RG-LRU block =================
  convertT<<<cv768, blk, 0, stream>>>(w_y, BV, C_, C_, 1, 0);                 // WtY  -> BV rows 0..767
  convertT<<<cv768, blk, 0, stream>>>(w_x, BV + W68, C_, C_, 1, 0);           // WtX  -> rows 768..1535
  convert_gw<<<H_, blk, 0, stream>>>(ig_w, ag_w, ig_b, ag_b, GW, GB);         // gates W -> F1 scratch
  norm_kernel<0><<<M_/4, blk, 0, stream>>>(x, tpre, nullptr, B0);             // xn -> B0
  mgemm<4,1,C_><<<g1536, blk, 0, stream>>>(B0, BV, b_y, b_x, F0b, 1536);      // yu [M][1536] -> F0b
  conv_kernel<<<(M_*LRU_)/256, blk, 0, stream>>>(F0b, conv_w, conv_b, B1, 1536, 768); // uc -> B1
  gates_mfma<<<dim3(M_/128, H_), blk, 0, stream>>>(B1, GW, GB, a_param, B2, BV); // a->B2, nx->BV
  scan_kernel<<<(N_*LRU_)/256, blk, 0, stream>>>(B2, BV, F0b, B0, 1536);      // hy -> B0 (y from yu)
  convertT<<<cv768, blk, 0, stream>>>(w_out, BV, C_, C_, 1, 0);               // Wt_out -> BV (nx dead)
  mgemm<1,0,C_><<<gN768, blk, 0, stream>>>(B0, BV, b_out, x, outF, C_);       // resid -> d_out (fp32)

  // ================= gated MLP (full-M) =================
  norm_kernel<0><<<M_/4, blk, 0, stream>>>(outF, cpre, nullptr, B0);          // z -> B0
  convertT<<<cvUp, blk, 0, stream>>>(ffw_up_w,       B1, C_, MLP_, 2, 0);     // Wt_up interleaved -> B1
  convertT<<<cvUp, blk, 0, stream>>>(ffw_up_w + WUP, B1, C_, MLP_, 2, 1);
  convertT<<<cvDn, blk, 0, stream>>>(ffw_dn_w, BV, MLP_, C_, 1, 0);           // Wt_dn -> BV
  {
    dim3 gUp(6144/128, M_/128);     // (48, 72)
    dim3 gDn(C_/128,   M_/128);     // (6, 72)
    mgemm<3,0,C_><<<gUp, blk, 0, stream>>>(B0, B1, ffw_up_b, nullptr, F0b, 6144); // g -> F0:F1
    mgemm<1,0,MLP_><<<gDn, blk, 0, stream>>>(F0b, BV, ffw_dn_b, outF, xsF, C_);   // xs (fp32) -> B0:B1
  }

  // ================= spatial ViT block =================
  norm_kernel<1><<<M_/4, blk, 0, stream>>>(xsF, ln1_s, ln1_b, B2);            // y1 -> B2
  convertT<<<cv768, blk, 0, stream>>>(wq, BV,          C_, C_, 1, 0);         // WtQ -> BV rows 0..767
  convertT<<<cv768, blk, 0, stream>>>(wk, BV + W68,    C_, C_, 1, 0);         // WtK -> rows 768..1535
  convertT<<<cv768, blk, 0, stream>>>(wv, BV + 2*W68,  C_, C_, 1, 0);
  convertT<<<cv768, blk, 0, stream>>>(wo, BV + 3*W68,  C_, C_, 1, 0);
  mgemm<4,0,C_><<<g1536, blk, 0, stream>>>(B2, BV, bq, bk, F0b, 1536);        // qk [M][1536] -> F0b
  mgemm<2,0,C_><<<gN768, blk, 0, stream>>>(B2, BV + 2*W68, bv, nullptr, F0b + 2*MC, C_); // Vt
  fattn<<<dim3(18, T_*H_), blk, 0, stream>>>(F0b, F0b + 2*MC, B2);            // sa -> B2 (y1 dead)
  mgemm<1,0,C_><<<gN768, blk, 0, stream>>>(B2, BV + 3*W68, bo, xsF, outF, C_); // xs2 -> d_out
  norm_kernel<1><<<M_/4, blk, 0, stream>>>(outF, ln2_s, ln2_b, B2);           // y2 -> B2
  convertT<<<cvUp, blk, 0, stream>>>(mlp_w1, B0b,       C_, MLP_, 1, 0);      // Wt_m1 -> B0:B1 (xs dead)
  convertT<<<cvDn, blk, 0, stream>>>(mlp_w2, B0b + WUP, MLP_, C_, 1, 0);      // Wt_m2 -> B0b+
  {
    dim3 gM1(MLP_/128, M_/128);     // (24, 72)
    dim3 gM2(C_/128,   M_/128);     // (6, 72)
    mgemm<0,1,C_><<<gM1, blk, 0, stream>>>(B2, B0b, mlp_b1, nullptr, F0b, MLP_);       // m1 -> F0:F1
    mgemm<1,0,MLP_><<<gM2, blk, 0, stream>>>(F0b, B0b + WUP, mlp_b2, outF, outF, C_);  // out (+resid)
  }
}

// Round 8
// 906.701 us; speedup vs baseline: 1.0318x; 1.0318x over previous
//
#include <hip/hip_runtime.h>
#include <hip/hip_bf16.h>

typedef __hip_bfloat16 bf16;
typedef __attribute__((ext_vector_type(4))) float f32x4;
typedef __attribute__((ext_vector_type(8))) short short8;
typedef __attribute__((ext_vector_type(4))) short s16x4;

#define T_ 8
#define N_ 1152
#define C_ 768
#define H_ 12
#define DH_ 64
#define MLP_ 3072
#define LRU_ 768
#define NIMG_ 1024
#define M_ (T_*N_)       // 9216 tokens

__device__ __forceinline__ float b2f(bf16 v){ return __bfloat162float(v); }
__device__ __forceinline__ bf16  f2b(float f){ return __float2bfloat16(f); }
__device__ __forceinline__ float bfs(short u){ return __uint_as_float(((unsigned int)(unsigned short)u) << 16); }
// fast tanh-gelu: tanh(u) = 1 - 2/(e^{2u}+1) via v_exp_f32; saturates correctly at +/-inf
__device__ __forceinline__ float gelu_tanh(float x){
  float x3 = x*x*x;
  float z = 1.5957691216057308f*(x + 0.044715f*x3);   // 2*0.7978845608028654
  float e = __expf(z);
  float t = 1.f - 2.f/(e + 1.f);
  return 0.5f*x*(1.f + t);
}
__device__ __forceinline__ void gll16(const void* g, void* l) {
  __builtin_amdgcn_global_load_lds((const __attribute__((address_space(1))) void*)g,
                                   (__attribute__((address_space(3))) void*)l, 16, 0, 0);
}
__device__ __forceinline__ f32x4 mfma16(short8 a, short8 b, f32x4 c) {
  return __builtin_amdgcn_mfma_f32_16x16x32_bf16(a, b, c, 0, 0, 0);
}

// ---------------- transpose-convert: W[K][N] fp32 -> Wt[(n*rs+ro)][K] bf16 ----------------
__global__ __launch_bounds__(256)
void convertT(const float* __restrict__ W, bf16* __restrict__ Wt, int Kd, int Nd,
              int rs, int ro) {
  __shared__ float tile[64][65];
  int k0 = blockIdx.y * 64, n0 = blockIdx.x * 64;
  int tid = threadIdx.x;
  int c = tid & 63, rr = tid >> 6;
  #pragma unroll
  for (int i = 0; i < 16; i++) {
    int r = rr * 16 + i;
    tile[r][c] = W[(size_t)(k0 + r) * Nd + n0 + c];
  }
  __syncthreads();
  #pragma unroll
  for (int i = 0; i < 16; i++) {
    int n = rr * 16 + i;
    Wt[(size_t)((n0 + n) * rs + ro) * Kd + k0 + c] = f2b(tile[c][n]);
  }
}

// batched variant: up to 4 (src,dst) jobs selected by blockIdx.z; ro = z*zro
struct CvJob  { const float* src; bf16* dst; };
struct CvJobs { CvJob j[4]; };
__global__ __launch_bounds__(256)
void convertT4(CvJobs jobs, int Kd, int Nd, int rs, int zro) {
  __shared__ float tile[64][65];
  int z = blockIdx.z;
  const float* __restrict__ W  = jobs.j[z].src;
  bf16* __restrict__ Wt        = jobs.j[z].dst;
  int ro = z * zro;
  int k0 = blockIdx.y * 64, n0 = blockIdx.x * 64;
  int tid = threadIdx.x;
  int c = tid & 63, rr = tid >> 6;
  #pragma unroll
  for (int i = 0; i < 16; i++) {
    int r = rr * 16 + i;
    tile[r][c] = W[(size_t)(k0 + r) * Nd + n0 + c];
  }
  __syncthreads();
  #pragma unroll
  for (int i = 0; i < 16; i++) {
    int n = rr * 16 + i;
    Wt[(size_t)((n0 + n) * rs + ro) * Kd + k0 + c] = f2b(tile[c][n]);
  }
}

// ---------------- gates weight interleave: GW[h][2e+s][d] bf16, GB[h][2e+s] ----------------
__global__ __launch_bounds__(256)
void convert_gw(const float* __restrict__ igw, const float* __restrict__ agw,
                const float* __restrict__ igb, const float* __restrict__ agb,
                bf16* __restrict__ GW, float* __restrict__ GB) {
  int h = blockIdx.x;
  for (int idx = threadIdx.x; idx < 128 * 64; idx += 256) {
    int rowc = idx >> 6;          // 2e+s
    int d    = idx & 63;
    int e    = rowc >> 1;
    const float* W = (rowc & 1) ? agw : igw;
    GW[((size_t)h * 128 + rowc) * 64 + d] = f2b(W[((size_t)h * 64 + d) * 64 + e]);
  }
  if (threadIdx.x < 128) {
    int rowc = threadIdx.x;
    GB[h * 128 + rowc] = ((rowc & 1) ? agb : igb)[h * 64 + (rowc >> 1)];
  }
}

// ---------------- MFMA GEMM: A[M,K] bf16 x Wt[N,K] bf16 -> out[M,N] ----------------
// Runtime-K rolled 2-buffer pipeline (R3/R5-verified; static-K unroll regressed via I$).
// EPI: 0 = bf16 out (+bias, opt gelu); 1 = fp32 out = v+bias+resid (resid may equal out);
//      2 = bf16 out scattered to V-transposed layout [t,h][d][n];
//      3 = interleaved gated-FFW: out[row][col>>1] = gelu(even+b0)*(odd+b1), bf16, width Nd/2
//      4 = split-bias merged pair: col<Nd/2 uses bias[], else bias2[]; gelu on first half iff ACT
template<int EPI, int ACT>
__global__ __launch_bounds__(256)
void mgemm(const bf16* __restrict__ A, const bf16* __restrict__ Wt,
           const float* __restrict__ bias, const float* __restrict__ bias2,
           void* __restrict__ outp, int K, int Nd) {
  __shared__ bf16 As[2][128][32];
  __shared__ bf16 Bs[2][128][32];
  int tid = threadIdx.x;
  int wave = tid >> 6, lane = tid & 63;
  int wm = wave >> 1, wn = wave & 1;
  int ln15 = lane & 15, quad = lane >> 4;
  int row0 = blockIdx.y * 128, col0 = blockIdx.x * 128;
  const bf16* ag = A  + (size_t)(row0 + wave*32 + (lane>>2)) * K + (lane&3)*8;
  const bf16* bg = Wt + (size_t)(col0 + wave*32 + (lane>>2)) * K + (lane&3)*8;
  f32x4 zero = {0.f, 0.f, 0.f, 0.f};
  f32x4 acc[4][4];
  #pragma unroll
  for (int i = 0; i < 4; i++)
    #pragma unroll
    for (int j = 0; j < 4; j++) acc[i][j] = zero;

  // prologue: stage tile 0 into buffer 0
  gll16(ag,          &As[0][wave*32][0]);
  gll16(ag + 16*K,   &As[0][wave*32 + 16][0]);
  gll16(bg,          &Bs[0][wave*32][0]);
  gll16(bg + 16*K,   &Bs[0][wave*32 + 16][0]);
  __syncthreads();

  int nt = K >> 5;
  int cur = 0;
  for (int t = 0; t < nt; ++t) {
    if (t + 1 < nt) {               // issue next-tile staging first (overlaps MFMA)
      int k1 = (t + 1) << 5;
      gll16(ag + k1,          &As[cur^1][wave*32][0]);
      gll16(ag + 16*K + k1,   &As[cur^1][wave*32 + 16][0]);
      gll16(bg + k1,          &Bs[cur^1][wave*32][0]);
      gll16(bg + 16*K + k1,   &Bs[cur^1][wave*32 + 16][0]);
    }
    short8 af[4], bf[4];
    #pragma unroll
    for (int i = 0; i < 4; i++)
      af[i] = *(const short8*)&As[cur][wm*64 + i*16 + ln15][quad*8];
    #pragma unroll
    for (int i = 0; i < 4; i++)
      bf[i] = *(const short8*)&Bs[cur][wn*64 + i*16 + ln15][quad*8];
    #pragma unroll
    for (int i = 0; i < 4; i++)
      #pragma unroll
      for (int j = 0; j < 4; j++)
        acc[i][j] = mfma16(af[i], bf[j], acc[i][j]);
    __syncthreads();
    cur ^= 1;
  }

  #pragma unroll
  for (int i = 0; i < 4; i++) {
    #pragma unroll
    for (int j = 0; j < 4; j++) {
      int col = col0 + wn*64 + j*16 + ln15;
      float bv;
      if (EPI == 3)      bv = bias[(col & 1) * (Nd >> 1) + (col >> 1)];
      else if (EPI == 4) bv = (col < (Nd >> 1)) ? bias[col] : bias2[col - (Nd >> 1)];
      else               bv = bias[col];
      #pragma unroll
      for (int r = 0; r < 4; r++) {
        int row = row0 + wm*64 + i*16 + quad*4 + r;
        float v = acc[i][j][r] + bv;
        if (EPI == 3) {
          float pv = __shfl_xor(v, 1, 64);
          if ((lane & 1) == 0)
            ((bf16*)outp)[(size_t)row * (Nd >> 1) + (col >> 1)] = f2b(gelu_tanh(v) * pv);
        } else if (EPI == 4) {
          if (ACT && col < (Nd >> 1)) v = gelu_tanh(v);
          ((bf16*)outp)[(size_t)row * Nd + col] = f2b(v);
        } else {
          if (ACT) v = gelu_tanh(v);
          if (EPI == 0) {
            ((bf16*)outp)[(size_t)row * Nd + col] = f2b(v);
          } else if (EPI == 1) {
            size_t o = (size_t)row * Nd + col;
            ((float*)outp)[o] = v + bias2[o];
          } else if (EPI == 2) {
            int tt = row / N_; int nn = row - tt * N_;
            ((bf16*)outp)[(((size_t)tt * H_ + (col >> 6)) * 64 + (col & 63)) * N_ + nn] = f2b(v);
          }
        }
      }
    }
  }
}

// ---------------- norm: one wave per token; fp32 in (float4), bf16 out (s16x4) ----------------
template<int LN>
__global__ __launch_bounds__(256)
void norm_kernel(const float* __restrict__ inp, const float* __restrict__ s,
                 const float* __restrict__ b, bf16* __restrict__ out) {
  int wid  = threadIdx.x >> 6;
  int lane = threadIdx.x & 63;
  int tok  = blockIdx.x * 4 + wid;
  const float* ip = inp + (size_t)tok*C_ + lane*4;
  f32x4 v[3];
  float sum = 0.f, sq = 0.f;
  #pragma unroll
  for (int i = 0; i < 3; i++) {
    v[i] = *(const f32x4*)(ip + i*256);
    #pragma unroll
    for (int j = 0; j < 4; j++) { sum += v[i][j]; sq += v[i][j]*v[i][j]; }
  }
  #pragma unroll
  for (int o = 32; o > 0; o >>= 1) {
    sum += __shfl_xor(sum, o, 64);
    sq  += __shfl_xor(sq, o, 64);
  }
  float scale, mean = 0.f;
  if (LN) {
    mean = sum * (1.f / C_);
    float var = sq * (1.f / C_) - mean * mean;
    scale = rsqrtf(var + 1e-6f);
  } else {
    scale = rsqrtf(sq * (1.f / C_) + 1e-6f);
  }
  #pragma unroll
  for (int i = 0; i < 3; i++) {
    int c0 = i*256 + lane*4;
    f32x4 sc = *(const f32x4*)(s + c0);
    f32x4 bb;
    if (LN) bb = *(const f32x4*)(b + c0);
    bf16 tmp[4];
    #pragma unroll
    for (int j = 0; j < 4; j++) {
      float r;
      if (LN) r = (v[i][j] - mean) * scale * sc[j] + bb[j];
      else    r = v[i][j] * scale * (1.f + sc[j]);
      tmp[j] = f2b(r);
    }
    *(s16x4*)(out + (size_t)tok*C_ + c0) = *(const s16x4*)tmp;
  }
}

// ---------------- causal depthwise temporal conv (width 4); u at [tok]*us + uo; short8 ----------------
__global__ __launch_bounds__(256)
void conv_kernel(const bf16* __restrict__ u0, const float* __restrict__ cw,
                 const float* __restrict__ cb, bf16* __restrict__ uc, int us, int uo) {
  int idx = blockIdx.x * 256 + threadIdx.x;   // M_*96 total
  int c8  = idx % (LRU_/8);
  int tok = idx / (LRU_/8);
  int ch0 = c8 * 8;
  int n = tok % N_;
  int t = tok / N_;
  float acc[8];
  {
    f32x4 b0 = *(const f32x4*)(cb + ch0);
    f32x4 b1 = *(const f32x4*)(cb + ch0 + 4);
    #pragma unroll
    for (int j = 0; j < 4; j++) { acc[j] = b0[j]; acc[4+j] = b1[j]; }
  }
  #pragma unroll
  for (int i = 0; i < 4; i++) {
    int tt = t - 3 + i;
    if (tt >= 0) {
      short8 v = *(const short8*)&u0[(size_t)(tt*N_ + n)*us + uo + ch0];
      f32x4 w0 = *(const f32x4*)(cw + i*LRU_ + ch0);
      f32x4 w1 = *(const f32x4*)(cw + i*LRU_ + ch0 + 4);
      #pragma unroll
      for (int j = 0; j < 4; j++) {
        acc[j]   += w0[j] * bfs(v[j]);
        acc[4+j] += w1[j] * bfs(v[4+j]);
      }
    }
  }
  bf16 tmp[8];
  #pragma unroll
  for (int j = 0; j < 8; j++) tmp[j] = f2b(acc[j]);
  *(short8*)&uc[(size_t)tok*LRU_ + ch0] = *(const short8*)tmp;
}

// ---------------- RG-LRU gates via MFMA (block-diagonal GEMM, interleaved ig/ag) ----------------
__global__ __launch_bounds__(256)
void gates_mfma(const bf16* __restrict__ uc, const bf16* __restrict__ GW,
                const float* __restrict__ GB, const float* __restrict__ ap,
                bf16* __restrict__ a_out, bf16* __restrict__ nx_out) {
  __shared__ bf16 As[128][64];   // u[row0+.., h*64 + d]  -> later: nx results
  __shared__ bf16 Bs[128][64];   // GW[h][2e+s][d]        -> later: a results
  int tid = threadIdx.x;
  int wave = tid >> 6, lane = tid & 63;
  int wm = wave >> 1, wn = wave & 1;
  int ln15 = lane & 15, quad = lane >> 4;
  int row0 = blockIdx.x * 128;
  int h = blockIdx.y;
  #pragma unroll
  for (int i = 0; i < 4; i++) {
    int chunk = wave * 4 + i;
    gll16(uc + (size_t)(row0 + chunk*8 + (lane>>3)) * LRU_ + h*DH_ + (lane&7)*8,
          &As[chunk*8][0]);
    gll16(GW + (size_t)h*128*64 + chunk*512 + lane*8, &Bs[chunk*8][0]);
  }
  __syncthreads();
  f32x4 zero = {0.f, 0.f, 0.f, 0.f};
  f32x4 acc[4][4];
  #pragma unroll
  for (int i = 0; i < 4; i++)
    #pragma unroll
    for (int j = 0; j < 4; j++) acc[i][j] = zero;
  short8 af0[4], af1[4], bf0[4], bf1[4];
  #pragma unroll
  for (int i = 0; i < 4; i++) {
    af0[i] = *(const short8*)&As[wm*64 + i*16 + ln15][quad*8];
    af1[i] = *(const short8*)&As[wm*64 + i*16 + ln15][32 + quad*8];
    bf0[i] = *(const short8*)&Bs[wn*64 + i*16 + ln15][quad*8];
    bf1[i] = *(const short8*)&Bs[wn*64 + i*16 + ln15][32 + quad*8];
  }
  #pragma unroll
  for (int i = 0; i < 4; i++)
    #pragma unroll
    for (int j = 0; j < 4; j++) {
      acc[i][j] = mfma16(af0[i], bf0[j], acc[i][j]);
      acc[i][j] = mfma16(af1[i], bf1[j], acc[i][j]);
    }
  __syncthreads();   // all waves done reading As/Bs fragments before overwrite

  int t_is0 = (row0 < N_);   // 128 | N_, so tiles never cross a t boundary
  int odd = lane & 1;
  float bvj[4], spj[4];
  #pragma unroll
  for (int j = 0; j < 4; j++) {
    int col = wn*64 + j*16 + ln15;
    bvj[j] = GB[h*128 + col];
    int e = col >> 1;
    float apv = ap[h*DH_ + e];
    spj[j] = (apv > 20.f) ? apv : log1pf(__expf(apv));
  }
  #pragma unroll
  for (int i = 0; i < 4; i++) {
    #pragma unroll
    for (int j = 0; j < 4; j++) {
      int col = wn*64 + j*16 + ln15;            // 2e+s; parity == lane parity
      int e = col >> 1;
      #pragma unroll
      for (int r = 0; r < 4; r++) {
        int lr = wm*64 + i*16 + quad*4 + r;     // local row
        float v = acc[i][j][r] + bvj[j];
        float g = 1.f / (1.f + __expf(-v));     // even: gx, odd: ga
        float mult = 1.f;
        if (odd) {
          float log_a = -8.f * g * spj[j];
          float a = __expf(log_a);
          mult = sqrtf(fmaxf(1.f - a*a, 0.f));  // exp(2*log_a) == a*a
          if (t_is0) { a = 0.f; mult = 1.f; }
          Bs[lr][e] = f2b(a);
        }
        float mp = __shfl_xor(mult, 1, 64);     // odd's mult -> even lane
        if (!odd) {
          float uv = b2f(As[lr][e]);            // u value lives in the A tile
          As[lr][e] = f2b(uv * g * mp);
        }
      }
    }
  }
  __syncthreads();
  // coalesced stores: 8 lanes x 16B = one full 128B row per 8 lanes
  int rr = tid >> 3, cc = (tid & 7) * 8;
  #pragma unroll
  for (int it = 0; it < 4; it++) {
    int row = it * 32 + rr;
    size_t o = (size_t)(row0 + row) * LRU_ + h*DH_ + cc;
    *(short8*)(nx_out + o) = *(const short8*)&As[row][cc];
    *(short8*)(a_out  + o) = *(const short8*)&Bs[row][cc];
  }
}

// ---------------- RG-LRU scan over t=8, fused h*y; y at [tok]*ys; short8 ----------------
__global__ __launch_bounds__(256)
void scan_kernel(const bf16* __restrict__ a, const bf16* __restrict__ nx,
                 const bf16* __restrict__ y, bf16* __restrict__ hy, int ys) {
  int idx = blockIdx.x * 256 + threadIdx.x;   // N_*96 total
  int c8 = idx % (LRU_/8);
  int n  = idx / (LRU_/8);
  int ch0 = c8 * 8;
  float h[8] = {0.f,0.f,0.f,0.f,0.f,0.f,0.f,0.f};
  #pragma unroll
  for (int t = 0; t < T_; t++) {
    size_t p = (size_t)(t*N_ + n) * LRU_ + ch0;
    short8 av = *(const short8*)(a + p);
    short8 nv = *(const short8*)(nx + p);
    short8 yv = *(const short8*)(y + (size_t)(t*N_ + n) * ys + ch0);
    bf16 tmp[8];
    #pragma unroll
    for (int j = 0; j < 8; j++) {
      h[j] = bfs(av[j]) * h[j] + bfs(nv[j]);
      tmp[j] = f2b(h[j] * bfs(yv[j]));
    }
    *(short8*)(hy + p) = *(const short8*)tmp;
  }
}

// ---------------- flash attention (MFMA), mask_image2image ----------------
// QK packed [tok][1536]: q at +0, k at +768 (both offset h*64). Vt: [t*H+h][64 d][1152 n].
__global__ __launch_bounds__(256)
void fattn(const bf16* __restrict__ QK, const bf16* __restrict__ Vt,
           bf16* __restrict__ O) {
  __shared__ bf16 Ks[128][64];      // [key][d]
  __shared__ bf16 VTs[64][128];     // [d][key]
  __shared__ bf16 Ps[4][16][128];   // per-wave P
  int qb = blockIdx.x, th = blockIdx.y;
  int h = th % H_, t = th / H_;
  int wave = threadIdx.x >> 6, lane = threadIdx.x & 63;
  int ln15 = lane & 15, quad = lane >> 4;
  int q0, kv0, nch;
  if (qb < 16) { q0 = qb * 64;            kv0 = NIMG_; nch = 1; }
  else         { q0 = NIMG_ + (qb-16)*64; kv0 = 0;     nch = 9; }
  int qw = q0 + wave * 16;
  const bf16* qp = QK + (size_t)(t*N_ + qw + ln15) * 1536 + h*DH_ + quad*8;
  short8 aq0 = *(const short8*)qp;
  short8 aq1 = *(const short8*)(qp + 32);
  f32x4 zero = {0.f, 0.f, 0.f, 0.f};
  f32x4 oacc[4];
  #pragma unroll
  for (int d = 0; d < 4; d++) oacc[d] = zero;
  float mi[4], li[4];
  #pragma unroll
  for (int r = 0; r < 4; r++) { mi[r] = -1e30f; li[r] = 0.f; }

  for (int ch = 0; ch < nch; ch++) {
    int kb = t*N_ + kv0 + ch*128;
    #pragma unroll
    for (int i = 0; i < 4; i++) {
      int r = wave*32 + i*8;
      gll16(QK + (size_t)(kb + r + (lane>>3))*1536 + 768 + h*DH_ + (lane&7)*8, &Ks[r][0]);
    }
    #pragma unroll
    for (int i = 0; i < 4; i++) {
      int d = wave*16 + i*4;
      gll16(Vt + ((size_t)(t*H_ + h)*64 + d + (lane>>4))*N_ + kv0 + ch*128 + ln15*8,
            &VTs[d][0]);
    }
    __syncthreads();
    // S = Q K^T * 0.125
    f32x4 s[8];
    #pragma unroll
    for (int nt = 0; nt < 8; nt++) {
      short8 b0 = *(const short8*)&Ks[nt*16 + ln15][quad*8];
      short8 b1 = *(const short8*)&Ks[nt*16 + ln15][32 + quad*8];
      f32x4 c_ = zero;
      c_ = mfma16(aq0, b0, c_);
      c_ = mfma16(aq1, b1, c_);
      #pragma unroll
      for (int r = 0; r < 4; r++) s[nt][r] = c_[r] * 0.125f;
    }
    // online softmax
    float alpha[4], lsum[4];
    #pragma unroll
    for (int r = 0; r < 4; r++) {
      float m_ = s[0][r];
      #pragma unroll
      for (int nt = 1; nt < 8; nt++) m_ = fmaxf(m_, s[nt][r]);
      #pragma unroll
      for (int o = 1; o < 16; o <<= 1) m_ = fmaxf(m_, __shfl_xor(m_, o, 64));
      float mnew = fmaxf(mi[r], m_);
      alpha[r] = __expf(mi[r] - mnew);
      mi[r] = mnew;
      lsum[r] = 0.f;
    }
    #pragma unroll
    for (int nt = 0; nt < 8; nt++)
      #pragma unroll
      for (int r = 0; r < 4; r++) {
        float p = __expf(s[nt][r] - mi[r]);
        s[nt][r] = p; lsum[r] += p;
      }
    #pragma unroll
    for (int r = 0; r < 4; r++) {
      float l_ = lsum[r];
      #pragma unroll
      for (int o = 1; o < 16; o <<= 1) l_ += __shfl_xor(l_, o, 64);
      li[r] = li[r] * alpha[r] + l_;
    }
    // P -> LDS (C-layout -> A-layout round trip)
    #pragma unroll
    for (int nt = 0; nt < 8; nt++)
      #pragma unroll
      for (int r = 0; r < 4; r++)
        Ps[wave][quad*4 + r][nt*16 + ln15] = f2b(s[nt][r]);
    #pragma unroll
    for (int d = 0; d < 4; d++)
      #pragma unroll
      for (int r = 0; r < 4; r++) oacc[d][r] *= alpha[r];
    // O += P V
    #pragma unroll
    for (int ks = 0; ks < 4; ks++) {
      short8 pa = *(const short8*)&Ps[wave][ln15][ks*32 + quad*8];
      #pragma unroll
      for (int dt = 0; dt < 4; dt++) {
        short8 vb = *(const short8*)&VTs[dt*16 + ln15][ks*32 + quad*8];
        oacc[dt] = mfma16(pa, vb, oacc[dt]);
      }
    }
    __syncthreads();
  }
  #pragma unroll
  for (int dt = 0; dt < 4; dt++)
    #pragma unroll
    for (int r = 0; r < 4; r++)
      O[(size_t)(t*N_ + qw + quad*4 + r)*C_ + h*DH_ + dt*16 + ln15]
        = f2b(oacc[dt][r] / li[r]);
}

extern "C" void kernel_launch(void* const* d_in, const int* in_sizes, int n_in,
                              void* d_out, int out_size, void* d_ws, size_t ws_size,
                              hipStream_t stream) {
  (void)in_sizes; (void)n_in; (void)out_size; (void)ws_size;
  const float* x        = (const float*)d_in[0];
  const float* tpre     = (const float*)d_in[1];
  const float* w_y      = (const float*)d_in[2];
  const float* b_y      = (const float*)d_in[3];
  const float* w_x      = (const float*)d_in[4];
  const float* b_x      = (const float*)d_in[5];
  const float* conv_w   = (const float*)d_in[6];
  const float* conv_b   = (const float*)d_in[7];
  const float* a_param  = (const float*)d_in[8];
  const float* ig_w     = (const float*)d_in[9];
  const float* ig_b     = (const float*)d_in[10];
  const float* ag_w     = (const float*)d_in[11];
  const float* ag_b     = (const float*)d_in[12];
  const float* w_out    = (const float*)d_in[13];
  const float* b_out    = (const float*)d_in[14];
  const float* cpre     = (const float*)d_in[15];
  const float* ffw_up_w = (const float*)d_in[16];
  const float* ffw_up_b = (const float*)d_in[17];
  const float* ffw_dn_w = (const float*)d_in[18];
  const float* ffw_dn_b = (const float*)d_in[19];
  const float* ln1_s    = (const float*)d_in[20];
  const float* ln1_b    = (const float*)d_in[21];
  const float* wq       = (const float*)d_in[22];
  const float* bq       = (const float*)d_in[23];
  const float* wk       = (const float*)d_in[24];
  const float* bk       = (const float*)d_in[25];
  const float* wv       = (const float*)d_in[26];
  const float* bv       = (const float*)d_in[27];
  const float* wo       = (const float*)d_in[28];
  const float* bo       = (const float*)d_in[29];
  const float* ln2_s    = (const float*)d_in[30];
  const float* ln2_b    = (const float*)d_in[31];
  const float* mlp_w1   = (const float*)d_in[32];
  const float* mlp_b1   = (const float*)d_in[33];
  const float* mlp_w2   = (const float*)d_in[34];
  const float* mlp_b2   = (const float*)d_in[35];

  const size_t MC = (size_t)M_ * C_;
  const size_t W68 = (size_t)C_ * C_;          // 589824 (768x768)
  const size_t WUP = (size_t)C_ * MLP_;        // 2.36M
  // ws layout: B0,B1,B2,BV bf16 M*C; F0,F1 fp32 M*C (F0:F1 = 4*MC bf16-equivalent)
  bf16* B0 = (bf16*)d_ws;
  bf16* B1 = B0 + MC;
  bf16* B2 = B1 + MC;
  bf16* BV = B2 + MC;
  float* F0 = (float*)(BV + MC);
  float* F1 = F0 + MC;
  bf16* F0b = (bf16*)F0;        // 56.6 MB scratch region (4*MC bf16 elems)
  bf16* B0b = (bf16*)B0;        // bf16 view of B0:B1 (28.3 MB)
  float* xsF = (float*)B0;      // fp32 view of B0:B1 (M x C fp32 = 28.3 MB)
  float* outF = (float*)d_out;  // resid / xs2 / final out (fp32 M x C)
  // F0b occupancy in temporal phase: yu [0,2MC); GW/GB at F1 (=2MC); WtO at [3MC,3MC+W68)
  bf16*  GW = (bf16*)F1;                        // [H][128][64] bf16 = 196 KiB
  float* GB = (float*)(GW + (size_t)H_*128*64); // [H][128] fp32
  bf16*  WtO = F0b + 3*MC;                      // w_out transposed

  dim3 blk(256);
  dim3 gN768(C_/128, M_/128);          // (6, 72)
  dim3 g1536(1536/128, M_/128);        // (12, 72)
  dim3 cvUp(48, 12);                   // 768x3072
  dim3 cvDn(12, 48);                   // 3072x768

  // ================= temporal RG-LRU block =================
  {
    CvJobs j1 = {{{w_y, BV}, {w_x, BV + W68}, {w_out, WtO}, {w_y, BV}}};
    convertT4<<<dim3(12, 12, 3), blk, 0, stream>>>(j1, C_, C_, 1, 0);         // WtY,WtX,WtO in one launch
  }
  convert_gw<<<H_, blk, 0, stream>>>(ig_w, ag_w, ig_b, ag_b, GW, GB);         // gates W -> F1 scratch
  norm_kernel<0><<<M_/4, blk, 0, stream>>>(x, tpre, nullptr, B0);             // xn -> B0
  mgemm<4,1><<<g1536, blk, 0, stream>>>(B0, BV, b_y, b_x, F0b, C_, 1536);     // yu [M][1536] -> F0b
  conv_kernel<<<(M_*(LRU_/8))/256, blk, 0, stream>>>(F0b, conv_w, conv_b, B1, 1536, 768); // uc -> B1
  gates_mfma<<<dim3(M_/128, H_), blk, 0, stream>>>(B1, GW, GB, a_param, B2, BV); // a->B2, nx->BV
  scan_kernel<<<(N_*(LRU_/8))/256, blk, 0, stream>>>(B2, BV, F0b, B0, 1536);  // hy -> B0 (y from yu)
  mgemm<1,0><<<gN768, blk, 0, stream>>>(B0, WtO, b_out, x, outF, C_, C_);     // resid -> d_out (fp32)

  // ================= gated MLP (full-M) =================
  norm_kernel<0><<<M_/4, blk, 0, stream>>>(outF, cpre, nullptr, B0);          // z -> B0
  {
    CvJobs j2 = {{{ffw_up_w, B1}, {ffw_up_w + WUP, B1}, {ffw_up_w, B1}, {ffw_up_w, B1}}};
    convertT4<<<dim3(48, 12, 2), blk, 0, stream>>>(j2, C_, MLP_, 2, 1);       // Wt_up interleaved -> B1
  }
  convertT<<<cvDn, blk, 0, stream>>>(ffw_dn_w, BV, MLP_, C_, 1, 0);           // Wt_dn -> BV (nx dead)
  {
    dim3 gUp(6144/128, M_/128);     // (48, 72)
    dim3 gDn(C_/128,   M_/128);     // (6, 72)
    mgemm<3,0><<<gUp, blk, 0, stream>>>(B0, B1, ffw_up_b, nullptr, F0b, C_, 6144); // g -> F0b[0,3MC)
    mgemm<1,0><<<gDn, blk, 0, stream>>>(F0b, BV, ffw_dn_b, outF, xsF, MLP_, C_);   // xs (fp32) -> B0:B1
  }

  // ================= spatial ViT block =================
  norm_kernel<1><<<M_/4, blk, 0, stream>>>(xsF, ln1_s, ln1_b, B2);            // y1 -> B2 (a dead)
  {
    CvJobs j3 = {{{wq, BV}, {wk, BV + W68}, {wv, BV + 2*W68}, {wo, BV + 3*W68}}};
    convertT4<<<dim3(12, 12, 4), blk, 0, stream>>>(j3, C_, C_, 1, 0);         // WtQ..WtO in one launch
  }
  mgemm<4,0><<<g1536, blk, 0, stream>>>(B2, BV, bq, bk, F0b, C_, 1536);       // qk [M][1536] -> F0b
  mgemm<2,0><<<gN768, blk, 0, stream>>>(B2, BV + 2*W68, bv, nullptr, F0b + 2*MC, C_, C_); // Vt
  fattn<<<dim3(18, T_*H_), blk, 0, stream>>>(F0b, F0b + 2*MC, B2);            // sa -> B2 (y1 dead)
  mgemm<1,0><<<gN768, blk, 0, stream>>>(B2, BV + 3*W68, bo, xsF, outF, C_, C_); // xs2 -> d_out
  norm_kernel<1><<<M_/4, blk, 0, stream>>>(outF, ln2_s, ln2_b, B2);           // y2 -> B2 (sa dead)
  convertT<<<cvUp, blk, 0, stream>>>(mlp_w1, B0b,       C_, MLP_, 1, 0);      // Wt_m1 -> B0:B1 (xs dead)
  convertT<<<cvDn, blk, 0, stream>>>(mlp_w2, B0b + WUP, MLP_, C_, 1, 0);      // Wt_m2 -> B0b+
  {
    dim3 gM1(MLP_/128, M_/128);     // (24, 72)
    dim3 gM2(C_/128,   M_/128);     // (6, 72)
    mgemm<0,1><<<gM1, blk, 0, stream>>>(B2, B0b, mlp_b1, nullptr, F0b, C_, MLP_);      // m1 -> F0b
    mgemm<1,0><<<gM2, blk, 0, stream>>>(F0b, B0b + WUP, mlp_b2, outF, outF, MLP_, C_); // out (+resid)
  }
}

// Round 9
// 885.702 us; speedup vs baseline: 1.0562x; 1.0237x over previous
//
#include <hip/hip_runtime.h>
#include <hip/hip_bf16.h>

typedef __hip_bfloat16 bf16;
typedef __attribute__((ext_vector_type(4))) float f32x4;
typedef __attribute__((ext_vector_type(8))) short short8;
typedef __attribute__((ext_vector_type(4))) short s16x4;

#define T_ 8
#define N_ 1152
#define C_ 768
#define H_ 12
#define DH_ 64
#define MLP_ 3072
#define LRU_ 768
#define NIMG_ 1024
#define M_ (T_*N_)       // 9216 tokens

__device__ __forceinline__ float b2f(bf16 v){ return __bfloat162float(v); }
__device__ __forceinline__ bf16  f2b(float f){ return __float2bfloat16(f); }
__device__ __forceinline__ float bfs(short u){ return __uint_as_float(((unsigned int)(unsigned short)u) << 16); }
// fast tanh-gelu: tanh(u) = 1 - 2/(e^{2u}+1) via v_exp_f32; saturates correctly at +/-inf
__device__ __forceinline__ float gelu_tanh(float x){
  float x3 = x*x*x;
  float z = 1.5957691216057308f*(x + 0.044715f*x3);   // 2*0.7978845608028654
  float e = __expf(z);
  float t = 1.f - 2.f/(e + 1.f);
  return 0.5f*x*(1.f + t);
}
__device__ __forceinline__ void gll16(const void* g, void* l) {
  __builtin_amdgcn_global_load_lds((const __attribute__((address_space(1))) void*)g,
                                   (__attribute__((address_space(3))) void*)l, 16, 0, 0);
}
__device__ __forceinline__ f32x4 mfma16(short8 a, short8 b, f32x4 c) {
  return __builtin_amdgcn_mfma_f32_16x16x32_bf16(a, b, c, 0, 0, 0);
}
// T1: XCD-aware bijective block remap (requires nwg % 8 == 0; true for all grids here)
__device__ __forceinline__ int xcd_swz(int flat, int nwg) {
  return (flat & 7) * (nwg >> 3) + (flat >> 3);
}

// ---------------- transpose-convert: W[K][N] fp32 -> Wt[(n*rs+ro)][K] bf16 ----------------
__global__ __launch_bounds__(256)
void convertT(const float* __restrict__ W, bf16* __restrict__ Wt, int Kd, int Nd,
              int rs, int ro) {
  __shared__ float tile[64][65];
  int k0 = blockIdx.y * 64, n0 = blockIdx.x * 64;
  int tid = threadIdx.x;
  int c = tid & 63, rr = tid >> 6;
  #pragma unroll
  for (int i = 0; i < 16; i++) {
    int r = rr * 16 + i;
    tile[r][c] = W[(size_t)(k0 + r) * Nd + n0 + c];
  }
  __syncthreads();
  #pragma unroll
  for (int i = 0; i < 16; i++) {
    int n = rr * 16 + i;
    Wt[(size_t)((n0 + n) * rs + ro) * Kd + k0 + c] = f2b(tile[c][n]);
  }
}

// batched variant: up to 4 (src,dst) jobs selected by blockIdx.z; ro = z*zro
struct CvJob  { const float* src; bf16* dst; };
struct CvJobs { CvJob j[4]; };
__global__ __launch_bounds__(256)
void convertT4(CvJobs jobs, int Kd, int Nd, int rs, int zro) {
  __shared__ float tile[64][65];
  int z = blockIdx.z;
  const float* __restrict__ W  = jobs.j[z].src;
  bf16* __restrict__ Wt        = jobs.j[z].dst;
  int ro = z * zro;
  int k0 = blockIdx.y * 64, n0 = blockIdx.x * 64;
  int tid = threadIdx.x;
  int c = tid & 63, rr = tid >> 6;
  #pragma unroll
  for (int i = 0; i < 16; i++) {
    int r = rr * 16 + i;
    tile[r][c] = W[(size_t)(k0 + r) * Nd + n0 + c];
  }
  __syncthreads();
  #pragma unroll
  for (int i = 0; i < 16; i++) {
    int n = rr * 16 + i;
    Wt[(size_t)((n0 + n) * rs + ro) * Kd + k0 + c] = f2b(tile[c][n]);
  }
}

// ---------------- gates weight interleave: GW[h][2e+s][d] bf16, GB[h][2e+s] ----------------
__global__ __launch_bounds__(256)
void convert_gw(const float* __restrict__ igw, const float* __restrict__ agw,
                const float* __restrict__ igb, const float* __restrict__ agb,
                bf16* __restrict__ GW, float* __restrict__ GB) {
  int h = blockIdx.x;
  for (int idx = threadIdx.x; idx < 128 * 64; idx += 256) {
    int rowc = idx >> 6;          // 2e+s
    int d    = idx & 63;
    int e    = rowc >> 1;
    const float* W = (rowc & 1) ? agw : igw;
    GW[((size_t)h * 128 + rowc) * 64 + d] = f2b(W[((size_t)h * 64 + d) * 64 + e]);
  }
  if (threadIdx.x < 128) {
    int rowc = threadIdx.x;
    GB[h * 128 + rowc] = ((rowc & 1) ? agb : igb)[h * 64 + (rowc >> 1)];
  }
}

// ---------------- MFMA GEMM: A[M,K] bf16 x Wt[N,K] bf16 -> out[M,N] ----------------
// Runtime-K rolled 2-buffer pipeline + T1 XCD block swizzle.
// EPI: 0 = bf16 out (+bias, opt gelu); 1 = fp32 out = v+bias+resid (resid may equal out);
//      2 = bf16 out scattered to V-transposed layout [t,h][d][n];
//      3 = interleaved gated-FFW: out[row][col>>1] = gelu(even+b0)*(odd+b1), bf16, width Nd/2
//      4 = split-bias merged pair: col<Nd/2 uses bias[], else bias2[]; gelu on first half iff ACT
template<int EPI, int ACT>
__global__ __launch_bounds__(256)
void mgemm(const bf16* __restrict__ A, const bf16* __restrict__ Wt,
           const float* __restrict__ bias, const float* __restrict__ bias2,
           void* __restrict__ outp, int K, int Nd) {
  __shared__ bf16 As[2][128][32];
  __shared__ bf16 Bs[2][128][32];
  int tid = threadIdx.x;
  int wave = tid >> 6, lane = tid & 63;
  int wm = wave >> 1, wn = wave & 1;
  int ln15 = lane & 15, quad = lane >> 4;
  int nf = xcd_swz(blockIdx.y * gridDim.x + blockIdx.x, gridDim.x * gridDim.y);
  int row0 = (nf / gridDim.x) * 128, col0 = (nf % gridDim.x) * 128;
  const bf16* ag = A  + (size_t)(row0 + wave*32 + (lane>>2)) * K + (lane&3)*8;
  const bf16* bg = Wt + (size_t)(col0 + wave*32 + (lane>>2)) * K + (lane&3)*8;
  f32x4 zero = {0.f, 0.f, 0.f, 0.f};
  f32x4 acc[4][4];
  #pragma unroll
  for (int i = 0; i < 4; i++)
    #pragma unroll
    for (int j = 0; j < 4; j++) acc[i][j] = zero;

  // prologue: stage tile 0 into buffer 0
  gll16(ag,          &As[0][wave*32][0]);
  gll16(ag + 16*K,   &As[0][wave*32 + 16][0]);
  gll16(bg,          &Bs[0][wave*32][0]);
  gll16(bg + 16*K,   &Bs[0][wave*32 + 16][0]);
  __syncthreads();

  int nt = K >> 5;
  int cur = 0;
  for (int t = 0; t < nt; ++t) {
    if (t + 1 < nt) {               // issue next-tile staging first (overlaps MFMA)
      int k1 = (t + 1) << 5;
      gll16(ag + k1,          &As[cur^1][wave*32][0]);
      gll16(ag + 16*K + k1,   &As[cur^1][wave*32 + 16][0]);
      gll16(bg + k1,          &Bs[cur^1][wave*32][0]);
      gll16(bg + 16*K + k1,   &Bs[cur^1][wave*32 + 16][0]);
    }
    short8 af[4], bf[4];
    #pragma unroll
    for (int i = 0; i < 4; i++)
      af[i] = *(const short8*)&As[cur][wm*64 + i*16 + ln15][quad*8];
    #pragma unroll
    for (int i = 0; i < 4; i++)
      bf[i] = *(const short8*)&Bs[cur][wn*64 + i*16 + ln15][quad*8];
    #pragma unroll
    for (int i = 0; i < 4; i++)
      #pragma unroll
      for (int j = 0; j < 4; j++)
        acc[i][j] = mfma16(af[i], bf[j], acc[i][j]);
    __syncthreads();
    cur ^= 1;
  }

  #pragma unroll
  for (int i = 0; i < 4; i++) {
    #pragma unroll
    for (int j = 0; j < 4; j++) {
      int col = col0 + wn*64 + j*16 + ln15;
      float bv;
      if (EPI == 3)      bv = bias[(col & 1) * (Nd >> 1) + (col >> 1)];
      else if (EPI == 4) bv = (col < (Nd >> 1)) ? bias[col] : bias2[col - (Nd >> 1)];
      else               bv = bias[col];
      #pragma unroll
      for (int r = 0; r < 4; r++) {
        int row = row0 + wm*64 + i*16 + quad*4 + r;
        float v = acc[i][j][r] + bv;
        if (EPI == 3) {
          float pv = __shfl_xor(v, 1, 64);
          if ((lane & 1) == 0)
            ((bf16*)outp)[(size_t)row * (Nd >> 1) + (col >> 1)] = f2b(gelu_tanh(v) * pv);
        } else if (EPI == 4) {
          if (ACT && col < (Nd >> 1)) v = gelu_tanh(v);
          ((bf16*)outp)[(size_t)row * Nd + col] = f2b(v);
        } else {
          if (ACT) v = gelu_tanh(v);
          if (EPI == 0) {
            ((bf16*)outp)[(size_t)row * Nd + col] = f2b(v);
          } else if (EPI == 1) {
            size_t o = (size_t)row * Nd + col;
            ((float*)outp)[o] = v + bias2[o];
          } else if (EPI == 2) {
            int tt = row / N_; int nn = row - tt * N_;
            ((bf16*)outp)[(((size_t)tt * H_ + (col >> 6)) * 64 + (col & 63)) * N_ + nn] = f2b(v);
          }
        }
      }
    }
  }
}

// ---------------- norm: one wave per token; fp32 in (float4), bf16 out (s16x4) ----------------
template<int LN>
__global__ __launch_bounds__(256)
void norm_kernel(const float* __restrict__ inp, const float* __restrict__ s,
                 const float* __restrict__ b, bf16* __restrict__ out) {
  int wid  = threadIdx.x >> 6;
  int lane = threadIdx.x & 63;
  int tok  = blockIdx.x * 4 + wid;
  const float* ip = inp + (size_t)tok*C_ + lane*4;
  f32x4 v[3];
  float sum = 0.f, sq = 0.f;
  #pragma unroll
  for (int i = 0; i < 3; i++) {
    v[i] = *(const f32x4*)(ip + i*256);
    #pragma unroll
    for (int j = 0; j < 4; j++) { sum += v[i][j]; sq += v[i][j]*v[i][j]; }
  }
  #pragma unroll
  for (int o = 32; o > 0; o >>= 1) {
    sum += __shfl_xor(sum, o, 64);
    sq  += __shfl_xor(sq, o, 64);
  }
  float scale, mean = 0.f;
  if (LN) {
    mean = sum * (1.f / C_);
    float var = sq * (1.f / C_) - mean * mean;
    scale = rsqrtf(var + 1e-6f);
  } else {
    scale = rsqrtf(sq * (1.f / C_) + 1e-6f);
  }
  #pragma unroll
  for (int i = 0; i < 3; i++) {
    int c0 = i*256 + lane*4;
    f32x4 sc = *(const f32x4*)(s + c0);
    f32x4 bb;
    if (LN) bb = *(const f32x4*)(b + c0);
    bf16 tmp[4];
    #pragma unroll
    for (int j = 0; j < 4; j++) {
      float r;
      if (LN) r = (v[i][j] - mean) * scale * sc[j] + bb[j];
      else    r = v[i][j] * scale * (1.f + sc[j]);
      tmp[j] = f2b(r);
    }
    *(s16x4*)(out + (size_t)tok*C_ + c0) = *(const s16x4*)tmp;
  }
}

// ---------------- RG-LRU gates via MFMA, conv FUSED into A-staging ----------------
// grid (72 row-tiles, 12 heads), T1-swizzled. Row-tiles never cross a t boundary
// (1152 = 9*128), so the conv tap mask is block-uniform. A-tile = conv(yu) computed
// in-register and ds_written to LDS (replaces the separate conv_kernel dispatch).
__global__ __launch_bounds__(256)
void gates_mfma(const bf16* __restrict__ yu, const float* __restrict__ cw,
                const float* __restrict__ cb, const bf16* __restrict__ GW,
                const float* __restrict__ GB, const float* __restrict__ ap,
                bf16* __restrict__ a_out, bf16* __restrict__ nx_out) {
  __shared__ bf16 As[128][64];   // u (conv output)     -> later: nx results
  __shared__ bf16 Bs[128][64];   // GW[h][2e+s][d]      -> later: a results
  int tid = threadIdx.x;
  int wave = tid >> 6, lane = tid & 63;
  int wm = wave >> 1, wn = wave & 1;
  int ln15 = lane & 15, quad = lane >> 4;
  int nf = xcd_swz(blockIdx.y * gridDim.x + blockIdx.x, gridDim.x * gridDim.y);
  int bx = nf % 72, h = nf / 72;
  int row0 = bx * 128;
  int tt0   = bx / 9;            // uniform t for this tile
  int nbase = (bx % 9) * 128;
  int rin = lane >> 3, colblk = lane & 7, ch0 = colblk * 8;
  f32x4 cb0 = *(const f32x4*)(cb + h*DH_ + ch0);
  f32x4 cb1 = *(const f32x4*)(cb + h*DH_ + ch0 + 4);
  #pragma unroll
  for (int i = 0; i < 4; i++) {
    int chunk = wave * 4 + i;
    gll16(GW + (size_t)h*128*64 + chunk*512 + lane*8, &Bs[chunk*8][0]);
    int row = chunk*8 + rin;
    int n = nbase + row;
    float acc8[8];
    #pragma unroll
    for (int j = 0; j < 4; j++) { acc8[j] = cb0[j]; acc8[4+j] = cb1[j]; }
    #pragma unroll
    for (int tap = 0; tap < 4; tap++) {
      int tt = tt0 - 3 + tap;
      if (tt >= 0) {
        short8 v = *(const short8*)&yu[(size_t)(tt*N_ + n)*1536 + 768 + h*DH_ + ch0];
        f32x4 w0 = *(const f32x4*)(cw + tap*LRU_ + h*DH_ + ch0);
        f32x4 w1 = *(const f32x4*)(cw + tap*LRU_ + h*DH_ + ch0 + 4);
        #pragma unroll
        for (int j = 0; j < 4; j++) {
          acc8[j]   += w0[j] * bfs(v[j]);
          acc8[4+j] += w1[j] * bfs(v[4+j]);
        }
      }
    }
    bf16 tmp[8];
    #pragma unroll
    for (int j = 0; j < 8; j++) tmp[j] = f2b(acc8[j]);
    *(short8*)&As[row][ch0] = *(const short8*)tmp;
  }
  __syncthreads();
  f32x4 zero = {0.f, 0.f, 0.f, 0.f};
  f32x4 acc[4][4];
  #pragma unroll
  for (int i = 0; i < 4; i++)
    #pragma unroll
    for (int j = 0; j < 4; j++) acc[i][j] = zero;
  short8 af0[4], af1[4], bf0[4], bf1[4];
  #pragma unroll
  for (int i = 0; i < 4; i++) {
    af0[i] = *(const short8*)&As[wm*64 + i*16 + ln15][quad*8];
    af1[i] = *(const short8*)&As[wm*64 + i*16 + ln15][32 + quad*8];
    bf0[i] = *(const short8*)&Bs[wn*64 + i*16 + ln15][quad*8];
    bf1[i] = *(const short8*)&Bs[wn*64 + i*16 + ln15][32 + quad*8];
  }
  #pragma unroll
  for (int i = 0; i < 4; i++)
    #pragma unroll
    for (int j = 0; j < 4; j++) {
      acc[i][j] = mfma16(af0[i], bf0[j], acc[i][j]);
      acc[i][j] = mfma16(af1[i], bf1[j], acc[i][j]);
    }
  __syncthreads();   // all waves done reading As/Bs fragments before overwrite

  int t_is0 = (tt0 == 0);
  int odd = lane & 1;
  float bvj[4], spj[4];
  #pragma unroll
  for (int j = 0; j < 4; j++) {
    int col = wn*64 + j*16 + ln15;
    bvj[j] = GB[h*128 + col];
    int e = col >> 1;
    float apv = ap[h*DH_ + e];
    spj[j] = (apv > 20.f) ? apv : log1pf(__expf(apv));
  }
  #pragma unroll
  for (int i = 0; i < 4; i++) {
    #pragma unroll
    for (int j = 0; j < 4; j++) {
      int col = wn*64 + j*16 + ln15;            // 2e+s; parity == lane parity
      int e = col >> 1;
      #pragma unroll
      for (int r = 0; r < 4; r++) {
        int lr = wm*64 + i*16 + quad*4 + r;     // local row
        float v = acc[i][j][r] + bvj[j];
        float g = 1.f / (1.f + __expf(-v));     // even: gx, odd: ga
        float mult = 1.f;
        if (odd) {
          float log_a = -8.f * g * spj[j];
          float a = __expf(log_a);
          mult = sqrtf(fmaxf(1.f - a*a, 0.f));  // exp(2*log_a) == a*a
          if (t_is0) { a = 0.f; mult = 1.f; }
          Bs[lr][e] = f2b(a);
        }
        float mp = __shfl_xor(mult, 1, 64);     // odd's mult -> even lane
        if (!odd) {
          float uv = b2f(As[lr][e]);            // u value lives in the A tile
          As[lr][e] = f2b(uv * g * mp);
        }
      }
    }
  }
  __syncthreads();
  // coalesced stores: 8 lanes x 16B = one full 128B row per 8 lanes
  int rr = tid >> 3, cc = (tid & 7) * 8;
  #pragma unroll
  for (int it = 0; it < 4; it++) {
    int row = it * 32 + rr;
    size_t o = (size_t)(row0 + row) * LRU_ + h*DH_ + cc;
    *(short8*)(nx_out + o) = *(const short8*)&As[row][cc];
    *(short8*)(a_out  + o) = *(const short8*)&Bs[row][cc];
  }
}

// ---------------- RG-LRU scan over t=8, fused h*y; y at [tok]*ys; short8 ----------------
__global__ __launch_bounds__(256)
void scan_kernel(const bf16* __restrict__ a, const bf16* __restrict__ nx,
                 const bf16* __restrict__ y, bf16* __restrict__ hy, int ys) {
  int idx = blockIdx.x * 256 + threadIdx.x;   // N_*96 total
  int c8 = idx % (LRU_/8);
  int n  = idx / (LRU_/8);
  int ch0 = c8 * 8;
  float h[8] = {0.f,0.f,0.f,0.f,0.f,0.f,0.f,0.f};
  #pragma unroll
  for (int t = 0; t < T_; t++) {
    size_t p = (size_t)(t*N_ + n) * LRU_ + ch0;
    short8 av = *(const short8*)(a + p);
    short8 nv = *(const short8*)(nx + p);
    short8 yv = *(const short8*)(y + (size_t)(t*N_ + n) * ys + ch0);
    bf16 tmp[8];
    #pragma unroll
    for (int j = 0; j < 8; j++) {
      h[j] = bfs(av[j]) * h[j] + bfs(nv[j]);
      tmp[j] = f2b(h[j] * bfs(yv[j]));
    }
    *(short8*)(hy + p) = *(const short8*)tmp;
  }
}

// ---------------- flash attention (MFMA), mask_image2image; T1-swizzled ----------------
// QK packed [tok][1536]: q at +0, k at +768 (both offset h*64). Vt: [t*H+h][64 d][1152 n].
__global__ __launch_bounds__(256)
void fattn(const bf16* __restrict__ QK, const bf16* __restrict__ Vt,
           bf16* __restrict__ O) {
  __shared__ bf16 Ks[128][64];      // [key][d]
  __shared__ bf16 VTs[64][128];     // [d][key]
  __shared__ bf16 Ps[4][16][128];   // per-wave P
  int nf = xcd_swz(blockIdx.y * gridDim.x + blockIdx.x, gridDim.x * gridDim.y);
  int qb = nf % 18, th = nf / 18;
  int h = th % H_, t = th / H_;
  int wave = threadIdx.x >> 6, lane = threadIdx.x & 63;
  int ln15 = lane & 15, quad = lane >> 4;
  int q0, kv0, nch;
  if (qb < 16) { q0 = qb * 64;            kv0 = NIMG_; nch = 1; }
  else         { q0 = NIMG_ + (qb-16)*64; kv0 = 0;     nch = 9; }
  int qw = q0 + wave * 16;
  const bf16* qp = QK + (size_t)(t*N_ + qw + ln15) * 1536 + h*DH_ + quad*8;
  short8 aq0 = *(const short8*)qp;
  short8 aq1 = *(const short8*)(qp + 32);
  f32x4 zero = {0.f, 0.f, 0.f, 0.f};
  f32x4 oacc[4];
  #pragma unroll
  for (int d = 0; d < 4; d++) oacc[d] = zero;
  float mi[4], li[4];
  #pragma unroll
  for (int r = 0; r < 4; r++) { mi[r] = -1e30f; li[r] = 0.f; }

  for (int ch = 0; ch < nch; ch++) {
    int kb = t*N_ + kv0 + ch*128;
    #pragma unroll
    for (int i = 0; i < 4; i++) {
      int r = wave*32 + i*8;
      gll16(QK + (size_t)(kb + r + (lane>>3))*1536 + 768 + h*DH_ + (lane&7)*8, &Ks[r][0]);
    }
    #pragma unroll
    for (int i = 0; i < 4; i++) {
      int d = wave*16 + i*4;
      gll16(Vt + ((size_t)(t*H_ + h)*64 + d + (lane>>4))*N_ + kv0 + ch*128 + ln15*8,
            &VTs[d][0]);
    }
    __syncthreads();
    // S = Q K^T * 0.125
    f32x4 s[8];
    #pragma unroll
    for (int nt = 0; nt < 8; nt++) {
      short8 b0 = *(const short8*)&Ks[nt*16 + ln15][quad*8];
      short8 b1 = *(const short8*)&Ks[nt*16 + ln15][32 + quad*8];
      f32x4 c_ = zero;
      c_ = mfma16(aq0, b0, c_);
      c_ = mfma16(aq1, b1, c_);
      #pragma unroll
      for (int r = 0; r < 4; r++) s[nt][r] = c_[r] * 0.125f;
    }
    // online softmax
    float alpha[4], lsum[4];
    #pragma unroll
    for (int r = 0; r < 4; r++) {
      float m_ = s[0][r];
      #pragma unroll
      for (int nt = 1; nt < 8; nt++) m_ = fmaxf(m_, s[nt][r]);
      #pragma unroll
      for (int o = 1; o < 16; o <<= 1) m_ = fmaxf(m_, __shfl_xor(m_, o, 64));
      float mnew = fmaxf(mi[r], m_);
      alpha[r] = __expf(mi[r] - mnew);
      mi[r] = mnew;
      lsum[r] = 0.f;
    }
    #pragma unroll
    for (int nt = 0; nt < 8; nt++)
      #pragma unroll
      for (int r = 0; r < 4; r++) {
        float p = __expf(s[nt][r] - mi[r]);
        s[nt][r] = p; lsum[r] += p;
      }
    #pragma unroll
    for (int r = 0; r < 4; r++) {
      float l_ = lsum[r];
      #pragma unroll
      for (int o = 1; o < 16; o <<= 1) l_ += __shfl_xor(l_, o, 64);
      li[r] = li[r] * alpha[r] + l_;
    }
    // P -> LDS (C-layout -> A-layout round trip)
    #pragma unroll
    for (int nt = 0; nt < 8; nt++)
      #pragma unroll
      for (int r = 0; r < 4; r++)
        Ps[wave][quad*4 + r][nt*16 + ln15] = f2b(s[nt][r]);
    #pragma unroll
    for (int d = 0; d < 4; d++)
      #pragma unroll
      for (int r = 0; r < 4; r++) oacc[d][r] *= alpha[r];
    // O += P V
    #pragma unroll
    for (int ks = 0; ks < 4; ks++) {
      short8 pa = *(const short8*)&Ps[wave][ln15][ks*32 + quad*8];
      #pragma unroll
      for (int dt = 0; dt < 4; dt++) {
        short8 vb = *(const short8*)&VTs[dt*16 + ln15][ks*32 + quad*8];
        oacc[dt] = mfma16(pa, vb, oacc[dt]);
      }
    }
    __syncthreads();
  }
  #pragma unroll
  for (int dt = 0; dt < 4; dt++)
    #pragma unroll
    for (int r = 0; r < 4; r++)
      O[(size_t)(t*N_ + qw + quad*4 + r)*C_ + h*DH_ + dt*16 + ln15]
        = f2b(oacc[dt][r] / li[r]);
}

extern "C" void kernel_launch(void* const* d_in, const int* in_sizes, int n_in,
                              void* d_out, int out_size, void* d_ws, size_t ws_size,
                              hipStream_t stream) {
  (void)in_sizes; (void)n_in; (void)out_size; (void)ws_size;
  const float* x        = (const float*)d_in[0];
  const float* tpre     = (const float*)d_in[1];
  const float* w_y      = (const float*)d_in[2];
  const float* b_y      = (const float*)d_in[3];
  const float* w_x      = (const float*)d_in[4];
  const float* b_x      = (const float*)d_in[5];
  const float* conv_w   = (const float*)d_in[6];
  const float* conv_b   = (const float*)d_in[7];
  const float* a_param  = (const float*)d_in[8];
  const float* ig_w     = (const float*)d_in[9];
  const float* ig_b     = (const float*)d_in[10];
  const float* ag_w     = (const float*)d_in[11];
  const float* ag_b     = (const float*)d_in[12];
  const float* w_out    = (const float*)d_in[13];
  const float* b_out    = (const float*)d_in[14];
  const float* cpre     = (const float*)d_in[15];
  const float* ffw_up_w = (const float*)d_in[16];
  const float* ffw_up_b = (const float*)d_in[17];
  const float* ffw_dn_w = (const float*)d_in[18];
  const float* ffw_dn_b = (const float*)d_in[19];
  const float* ln1_s    = (const float*)d_in[20];
  const float* ln1_b    = (const float*)d_in[21];
  const float* wq       = (const float*)d_in[22];
  const float* bq       = (const float*)d_in[23];
  const float* wk       = (const float*)d_in[24];
  const float* bk       = (const float*)d_in[25];
  const float* wv       = (const float*)d_in[26];
  const float* bv       = (const float*)d_in[27];
  const float* wo       = (const float*)d_in[28];
  const float* bo       = (const float*)d_in[29];
  const float* ln2_s    = (const float*)d_in[30];
  const float* ln2_b    = (const float*)d_in[31];
  const float* mlp_w1   = (const float*)d_in[32];
  const float* mlp_b1   = (const float*)d_in[33];
  const float* mlp_w2   = (const float*)d_in[34];
  const float* mlp_b2   = (const float*)d_in[35];

  const size_t MC = (size_t)M_ * C_;
  const size_t W68 = (size_t)C_ * C_;          // 589824 (768x768)
  const size_t WUP = (size_t)C_ * MLP_;        // 2.36M
  // ws layout: B0,B1,B2,BV bf16 M*C; F0,F1 fp32 M*C (F0:F1 = 4*MC bf16-equivalent)
  bf16* B0 = (bf16*)d_ws;
  bf16* B1 = B0 + MC;
  bf16* B2 = B1 + MC;
  bf16* BV = B2 + MC;
  float* F0 = (float*)(BV + MC);
  float* F1 = F0 + MC;
  bf16* F0b = (bf16*)F0;        // 56.6 MB scratch region (4*MC bf16 elems)
  bf16* B0b = (bf16*)B0;        // bf16 view of B0:B1 (28.3 MB)
  float* xsF = (float*)B0;      // fp32 view of B0:B1 (M x C fp32 = 28.3 MB)
  float* outF = (float*)d_out;  // resid / xs2 / final out (fp32 M x C)
  // F0b occupancy in temporal phase: yu [0,2MC); GW/GB at F1 (=2MC); WtO at [3MC,3MC+W68)
  bf16*  GW = (bf16*)F1;                        // [H][128][64] bf16 = 196 KiB
  float* GB = (float*)(GW + (size_t)H_*128*64); // [H][128] fp32
  bf16*  WtO = F0b + 3*MC;                      // w_out transposed

  dim3 blk(256);
  dim3 gN768(C_/128, M_/128);          // (6, 72)
  dim3 g1536(1536/128, M_/128);        // (12, 72)
  dim3 cvUp(48, 12);                   // 768x3072
  dim3 cvDn(12, 48);                   // 3072x768

  // ================= temporal RG-LRU block =================
  {
    CvJobs j1 = {{{w_y, BV}, {w_x, BV + W68}, {w_out, WtO}, {w_y, BV}}};
    convertT4<<<dim3(12, 12, 3), blk, 0, stream>>>(j1, C_, C_, 1, 0);         // WtY,WtX,WtO in one launch
  }
  convert_gw<<<H_, blk, 0, stream>>>(ig_w, ag_w, ig_b, ag_b, GW, GB);         // gates W -> F1 scratch
  norm_kernel<0><<<M_/4, blk, 0, stream>>>(x, tpre, nullptr, B0);             // xn -> B0
  mgemm<4,1><<<g1536, blk, 0, stream>>>(B0, BV, b_y, b_x, F0b, C_, 1536);     // yu [M][1536] -> F0b
  gates_mfma<<<dim3(72, H_), blk, 0, stream>>>(F0b, conv_w, conv_b, GW, GB,
                                               a_param, B2, BV);              // conv+gates: a->B2, nx->BV
  scan_kernel<<<(N_*(LRU_/8))/256, blk, 0, stream>>>(B2, BV, F0b, B0, 1536);  // hy -> B0 (y from yu)
  mgemm<1,0><<<gN768, blk, 0, stream>>>(B0, WtO, b_out, x, outF, C_, C_);     // resid -> d_out (fp32)

  // ================= gated MLP (full-M) =================
  norm_kernel<0><<<M_/4, blk, 0, stream>>>(outF, cpre, nullptr, B0);          // z -> B0
  {
    CvJobs j2 = {{{ffw_up_w, B1}, {ffw_up_w + WUP, B1}, {ffw_up_w, B1}, {ffw_up_w, B1}}};
    convertT4<<<dim3(48, 12, 2), blk, 0, stream>>>(j2, C_, MLP_, 2, 1);       // Wt_up interleaved -> B1
  }
  convertT<<<cvDn, blk, 0, stream>>>(ffw_dn_w, BV, MLP_, C_, 1, 0);           // Wt_dn -> BV (nx dead)
  {
    dim3 gUp(6144/128, M_/128);     // (48, 72)
    dim3 gDn(C_/128,   M_/128);     // (6, 72)
    mgemm<3,0><<<gUp, blk, 0, stream>>>(B0, B1, ffw_up_b, nullptr, F0b, C_, 6144); // g -> F0b[0,3MC)
    mgemm<1,0><<<gDn, blk, 0, stream>>>(F0b, BV, ffw_dn_b, outF, xsF, MLP_, C_);   // xs (fp32) -> B0:B1
  }

  // ================= spatial ViT block =================
  norm_kernel<1><<<M_/4, blk, 0, stream>>>(xsF, ln1_s, ln1_b, B2);            // y1 -> B2 (a dead)
  {
    CvJobs j3 = {{{wq, BV}, {wk, BV + W68}, {wv, BV + 2*W68}, {wo, BV + 3*W68}}};
    convertT4<<<dim3(12, 12, 4), blk, 0, stream>>>(j3, C_, C_, 1, 0);         // WtQ..WtO in one launch
  }
  mgemm<4,0><<<g1536, blk, 0, stream>>>(B2, BV, bq, bk, F0b, C_, 1536);       // qk [M][1536] -> F0b
  mgemm<2,0><<<gN768, blk, 0, stream>>>(B2, BV + 2*W68, bv, nullptr, F0b + 2*MC, C_, C_); // Vt
  fattn<<<dim3(18, T_*H_), blk, 0, stream>>>(F0b, F0b + 2*MC, B2);            // sa -> B2 (y1 dead)
  mgemm<1,0><<<gN768, blk, 0, stream>>>(B2, BV + 3*W68, bo, xsF, outF, C_, C_); // xs2 -> d_out
  norm_kernel<1><<<M_/4, blk, 0, stream>>>(outF, ln2_s, ln2_b, B2);           // y2 -> B2 (sa dead)
  convertT<<<cvUp, blk, 0, stream>>>(mlp_w1, B0b,       C_, MLP_, 1, 0);      // Wt_m1 -> B0:B1 (xs dead)
  convertT<<<cvDn, blk, 0, stream>>>(mlp_w2, B0b + WUP, MLP_, C_, 1, 0);      // Wt_m2 -> B0b+
  {
    dim3 gM1(MLP_/128, M_/128);     // (24, 72)
    dim3 gM2(C_/128,   M_/128);     // (6, 72)
    mgemm<0,1><<<gM1, blk, 0, stream>>>(B2, B0b, mlp_b1, nullptr, F0b, C_, MLP_);      // m1 -> F0b
    mgemm<1,0><<<gM2, blk, 0, stream>>>(F0b, B0b + WUP, mlp_b2, outF, outF, MLP_, C_); // out (+resid)
  }
}